// Round 15
// baseline (2659.439 us; speedup 1.0000x reference)
//
#include <hip/hip_runtime.h>
#include <math.h>

#define B 64
#define T 512
#define II 512
#define H 512
#define NBLK 256
#define POLL_CAP 65536

typedef float f32x4 __attribute__((ext_vector_type(4)));
typedef short s16x8 __attribute__((ext_vector_type(8)));
typedef unsigned u32;
typedef unsigned long long u64;

union pk8 { s16x8 v; u32 u[4]; };

__device__ __forceinline__ unsigned short f2b(float f){
  union { float f; u32 u; } v; v.f = f;
  u32 r = v.u + 0x7fffu + ((v.u >> 16) & 1u);
  return (unsigned short)(r >> 16);
}

__device__ __forceinline__ s16x8 cvt8(float4 lo, float4 hi){
  pk8 r;
  asm("v_cvt_pk_bf16_f32 %0, %1, %2" : "=v"(r.u[0]) : "v"(lo.x), "v"(lo.y));
  asm("v_cvt_pk_bf16_f32 %0, %1, %2" : "=v"(r.u[1]) : "v"(lo.z), "v"(lo.w));
  asm("v_cvt_pk_bf16_f32 %0, %1, %2" : "=v"(r.u[2]) : "v"(hi.x), "v"(hi.y));
  asm("v_cvt_pk_bf16_f32 %0, %1, %2" : "=v"(r.u[3]) : "v"(hi.z), "v"(hi.w));
  return r.v;
}

__device__ __forceinline__ float sigm_(float x){
  return __builtin_amdgcn_rcpf(1.f + __expf(-x));
}
__device__ __forceinline__ float tanh_(float x){
  float t = __expf(-2.f * fabsf(x));
  float r = (1.f - t) * __builtin_amdgcn_rcpf(1.f + t);
  return copysignf(r, x);
}

// ---- XCD-local (L2-scope) ops: sc0 = gfx950 glc (bypass L1, read/write L2) ----
__device__ __forceinline__ u32 ld_sc0_u32(const u32* p){
  u32 v;
  asm volatile("global_load_dword %0, %1, off sc0\n\ts_waitcnt vmcnt(0)"
               : "=v"(v) : "v"(p) : "memory");
  return v;
}
__device__ __forceinline__ void st_sc0_u32(u32* p, u32 v){
  asm volatile("global_store_dword %0, %1, off sc0" : : "v"(p), "v"(v) : "memory");
}
__device__ __forceinline__ void ld4_sc0_issue(const void* p0, const void* p1,
                                              const void* p2, const void* p3,
                                              uint4& a, uint4& b, uint4& c, uint4& d){
  asm volatile(
    "global_load_dwordx4 %0, %4, off sc0\n\t"
    "global_load_dwordx4 %1, %5, off sc0\n\t"
    "global_load_dwordx4 %2, %6, off sc0\n\t"
    "global_load_dwordx4 %3, %7, off sc0"
    : "=&v"(a), "=&v"(b), "=&v"(c), "=&v"(d)
    : "v"(p0), "v"(p1), "v"(p2), "v"(p3)
    : "memory");
}

__global__ void init_ws(u32* p, int n){
  int i = blockIdx.x*blockDim.x + threadIdx.x;
  for (; i < n; i += gridDim.x*blockDim.x)
    __hip_atomic_store(p + i, 0u, __ATOMIC_RELAXED, __HIP_MEMORY_SCOPE_AGENT);
}

// Persistent bidirectional LSTM. 256 blocks x 256 threads, 1 block/CU (LDS-forced).
// Sync v15 = r11's compute verbatim, with 2-of-4 rendezvous removed:
//  - barrier P deleted: ALL waves poll the group flag line independently (bounded).
//    Safe: own-block flag(s+1) implies all 4 waves finished elementwise(s), which
//    follows their Hlds/g_lds reads; g_lds WAR is covered by barrier A(s+1).
//  - barrier C deleted: each wave drains its h-stores (vmcnt 0) then ds_add's a
//    monotonic LDS counter; the LAST arriver (old==4s+3) posts the flag. No wave
//    ever waits on the counter -> hang-impossible.
// Remaining per-step barriers: A (Hlds ready), B (g_lds ready).
__global__ __launch_bounds__(256, 1) void lstm_persistent(
    const float* __restrict__ xs,
    const float* __restrict__ Wih_f, const float* __restrict__ Whh_f,
    const float* __restrict__ bih_f, const float* __restrict__ bhh_f,
    const float* __restrict__ Wih_b, const float* __restrict__ Whh_b,
    const float* __restrict__ bih_b, const float* __restrict__ bhh_b,
    float* __restrict__ out,
    u32* __restrict__ flags,     // [8 groups][32] u32 = one 128B line per group
    u32* __restrict__ roster,    // [8] claim counters (agent scope, once)
    u32* __restrict__ hbuf0, u32* __restrict__ hbuf1)  // [2][B][H/2] u32 each
{
  __shared__ unsigned short Wlds[4*16*1024];   // 128 KB bf16, swizzled
  __shared__ unsigned short Hlds[16*512];      // 16 KB bf16, swizzled
  __shared__ float g_lds[4][16][16];
  __shared__ float bias_s[64];
  __shared__ u32 role_s;
  __shared__ u32 cnt_s;

  const int tid = threadIdx.x;

  // ---- role discovery: physical XCD id + roster slot (one agent RMW, once) ----
  if (tid == 0){
    u32 xcc;
    asm volatile("s_getreg_b32 %0, hwreg(HW_REG_XCC_ID, 0, 32)" : "=s"(xcc));
    xcc &= 7u;
    u32 slot = __hip_atomic_fetch_add(&roster[xcc], 1u,
                                      __ATOMIC_RELAXED, __HIP_MEMORY_SCOPE_AGENT);
    role_s = (xcc << 5) | (slot & 31u);
    cnt_s = 0u;
  }
  __syncthreads();
  const u32 role = role_s;
  const int grp   = role >> 5;        // = physical XCD id
  const int qtile = role & 31;
  const int dir   = grp >> 2;
  const int btile = grp & 3;
  const int q0 = qtile * 16;
  const int b0 = btile * 16;

  const float* __restrict__ Wih = dir ? Wih_b : Wih_f;
  const float* __restrict__ Whh = dir ? Whh_b : Whh_f;
  const float* __restrict__ bih = dir ? bih_b : bih_f;
  const float* __restrict__ bhh = dir ? bhh_b : bhh_f;

  // ---- stage weights into LDS (bf16, XOR-swizzled), once ----
  for (int it = 0; it < 32; ++it){
    int idx = it * 256 + tid;
    int c64 = idx >> 7;
    int k   = (idx & 127) * 8;
    int cg  = (c64 >> 4) * H + q0 + (c64 & 15);
    const float* src = (k < II) ? (Wih + (size_t)cg * II + k)
                                : (Whh + (size_t)cg * H + (k - II));
    float4 lo = *(const float4*)src;
    float4 hi = *(const float4*)(src + 4);
    s16x8 v;
    v[0]=(short)f2b(lo.x); v[1]=(short)f2b(lo.y); v[2]=(short)f2b(lo.z); v[3]=(short)f2b(lo.w);
    v[4]=(short)f2b(hi.x); v[5]=(short)f2b(hi.y); v[6]=(short)f2b(hi.z); v[7]=(short)f2b(hi.w);
    u32 byte = ((u32)c64 * 2048u + (u32)k * 2u) ^ (((u32)(c64 & 7)) << 4);
    *(s16x8*)((char*)Wlds + byte) = v;
  }
  if (tid < 64){
    int g = tid >> 4, jj = tid & 15;
    int cg = g * H + q0 + jj;
    bias_s[tid] = bih[cg] + bhh[cg];
  }
  __syncthreads();

  const int w = tid >> 6;                 // wave = gate type
  const int l = tid & 63;
  const int arow = b0 + (l & 15);
  const int kgrp = (l >> 4) * 8;
  const int c64w = (w << 4) | (l & 15);
  const u32 swz   = ((u32)(c64w & 7)) << 4;
  const u32 wbase = (u32)c64w * 2048u;
  const u32 hrb = (u32)(l & 15) * 1024u;  // Hlds A-frag row base
  const u32 hsz = ((u32)(l & 7)) << 4;

  // Hlds staging: wave w stages rows 4w..4w+3; lane covers 16B of each row
  const int sr = w * 4;
  const int si = l;

  const int eb = tid >> 4;
  const int ej = tid & 15;
  float c_reg = 0.f;

  const size_t hdir = (size_t)dir * (B * (H/2));   // u32 units
  u32* const fl = flags + grp * 32;

  // ---- prologue: x-half for step 0 (seeds step 0's h-MFMA accumulators) ----
  f32x4 acc_xa_n = {0.f,0.f,0.f,0.f}, acc_xb_n = {0.f,0.f,0.f,0.f};
  {
    const int t0 = dir ? (T-1) : 0;
    const float* xrow = xs + ((size_t)arow * T + t0) * II + kgrp;
    #pragma unroll
    for (int ks = 0; ks < 8; ++ks){
      s16x8 a0 = cvt8(*(const float4*)(xrow + ks*32),     *(const float4*)(xrow + ks*32 + 4));
      s16x8 a1 = cvt8(*(const float4*)(xrow + (ks+8)*32), *(const float4*)(xrow + (ks+8)*32 + 4));
      u32 byte0 = (wbase + (u32)(ks*32 + kgrp) * 2u) ^ swz;
      u32 byte1 = (wbase + (u32)((ks+8)*32 + kgrp) * 2u) ^ swz;
      s16x8 b0f = *(const s16x8*)((const char*)Wlds + byte0);
      s16x8 b1f = *(const s16x8*)((const char*)Wlds + byte1);
      acc_xa_n = __builtin_amdgcn_mfma_f32_16x16x32_bf16(a0, b0f, acc_xa_n, 0, 0, 0);
      acc_xb_n = __builtin_amdgcn_mfma_f32_16x16x32_bf16(a1, b1f, acc_xb_n, 0, 0, 0);
    }
  }

  #pragma unroll 1
  for (int s = 0; s < T; ++s){
    const int t = dir ? (T - 1 - s) : s;
    const u32* __restrict__ hin  = (s & 1) ? hbuf1 : hbuf0;
    u32* __restrict__       hout = (s & 1) ? hbuf0 : hbuf1;

    // ---- 1: ALL waves poll group flag line independently (bounded, no barrier) ----
    if (s > 0){
      const u32* fp = fl + (l & 31);
      for (int it = 0; it < POLL_CAP; ++it){
        u32 v = ld_sc0_u32(fp);
        if (__all((int)(v >= (u32)s))) break;
        __builtin_amdgcn_s_sleep(1);
      }
    }

    // ---- 2: h loads (4 x dwordx4 sc0, coalesced) -> Hlds (swizzled) ----
    const char* hinb = (const char*)(hin + hdir);
    const char* r0p = hinb + (size_t)(b0 + sr + 0) * 1024 + (size_t)si * 16;
    const char* r1p = r0p + 1024;
    const char* r2p = r0p + 2048;
    const char* r3p = r0p + 3072;
    uint4 hva, hvb, hvc, hvd;
    ld4_sc0_issue(r0p, r1p, r2p, r3p, hva, hvb, hvc, hvd);
    asm volatile("s_waitcnt vmcnt(0)" ::: "memory");
    __builtin_amdgcn_sched_barrier(0);
    {
      u32 byte0 = ((u32)(sr+0) * 1024u + (u32)si * 16u) ^ (((u32)((sr+0) & 7)) << 4);
      u32 byte1 = ((u32)(sr+1) * 1024u + (u32)si * 16u) ^ (((u32)((sr+1) & 7)) << 4);
      u32 byte2 = ((u32)(sr+2) * 1024u + (u32)si * 16u) ^ (((u32)((sr+2) & 7)) << 4);
      u32 byte3 = ((u32)(sr+3) * 1024u + (u32)si * 16u) ^ (((u32)((sr+3) & 7)) << 4);
      *(uint4*)((char*)Hlds + byte0) = hva;
      *(uint4*)((char*)Hlds + byte1) = hvb;
      *(uint4*)((char*)Hlds + byte2) = hvc;
      *(uint4*)((char*)Hlds + byte3) = hvd;
    }
    __syncthreads();                       // BARRIER A

    // ---- 3: h-half MFMAs, accumulators SEEDED with precomputed x-half ----
    f32x4 acc_ha = acc_xa_n, acc_hb = acc_xb_n;
    #pragma unroll
    for (int ks = 0; ks < 8; ++ks){
      u32 hb0 = (hrb + (u32)(ks*64 + (kgrp*2))) ^ hsz;
      u32 hb1 = (hrb + (u32)((ks+8)*64 + (kgrp*2))) ^ hsz;
      s16x8 a0 = *(const s16x8*)((const char*)Hlds + hb0);
      s16x8 a1 = *(const s16x8*)((const char*)Hlds + hb1);
      u32 byte0 = (wbase + (u32)(II + ks*32 + kgrp) * 2u) ^ swz;
      u32 byte1 = (wbase + (u32)(II + (ks+8)*32 + kgrp) * 2u) ^ swz;
      s16x8 b0f = *(const s16x8*)((const char*)Wlds + byte0);
      s16x8 b1f = *(const s16x8*)((const char*)Wlds + byte1);
      acc_ha = __builtin_amdgcn_mfma_f32_16x16x32_bf16(a0, b0f, acc_ha, 0, 0, 0);
      acc_hb = __builtin_amdgcn_mfma_f32_16x16x32_bf16(a1, b1f, acc_hb, 0, 0, 0);
    }

    // ---- 4: gates to LDS ----
    #pragma unroll
    for (int r = 0; r < 4; ++r){
      int bl = (l >> 4) * 4 + r;
      g_lds[w][bl][l & 15] = acc_ha[r] + acc_hb[r];
    }
    __syncthreads();                       // BARRIER B

    // ---- 5: elementwise update; publish packed h (sc0 -> local L2) ----
    float hn;
    {
      float gi = g_lds[0][eb][ej] + bias_s[ej];
      float gf = g_lds[1][eb][ej] + bias_s[16 + ej];
      float gg = g_lds[2][eb][ej] + bias_s[32 + ej];
      float go = g_lds[3][eb][ej] + bias_s[48 + ej];
      float si_ = sigm_(gi);
      float sf  = sigm_(gf);
      float tg  = tanh_(gg);
      float so  = sigm_(go);
      c_reg = sf * c_reg + si_ * tg;
      hn = so * tanh_(c_reg);
      u32 hb = (u32)f2b(hn);
      u32 nb = (u32)__shfl_xor((int)hb, 1, 64);
      if (!(tid & 1)){
        u32* p = hout + hdir + (size_t)(b0 + eb) * (H/2) + (size_t)((q0 + ej) >> 1);
        st_sc0_u32(p, hb | (nb << 16));
      }
    }

    // ---- 6: per-wave drain + LDS-counter arrival; LAST wave posts the flag ----
    asm volatile("s_waitcnt vmcnt(0)" ::: "memory");   // this wave's h stores in L2
    if (l == 0){
      u32 old = __hip_atomic_fetch_add(&cnt_s, 1u,
                                       __ATOMIC_ACQ_REL, __HIP_MEMORY_SCOPE_WORKGROUP);
      if (old == (u32)(4*s + 3) && s + 1 < T)
        st_sc0_u32(&fl[qtile], (u32)(s + 1));
    }

    // ---- 7: tail (overlaps peers' catch-up): out store + NEXT x-half ----
    out[((size_t)(b0+eb) * T + t) * (2*H) + (size_t)dir * H + (q0 + ej)] = hn;
    if (s + 1 < T){
      const int tn = dir ? (T - 2 - s) : (s + 1);
      const float* xrow = xs + ((size_t)arow * T + tn) * II + kgrp;
      f32x4 na = {0.f,0.f,0.f,0.f}, nb2 = {0.f,0.f,0.f,0.f};
      #pragma unroll
      for (int ks = 0; ks < 8; ++ks){
        s16x8 a0 = cvt8(*(const float4*)(xrow + ks*32),     *(const float4*)(xrow + ks*32 + 4));
        s16x8 a1 = cvt8(*(const float4*)(xrow + (ks+8)*32), *(const float4*)(xrow + (ks+8)*32 + 4));
        u32 byte0 = (wbase + (u32)(ks*32 + kgrp) * 2u) ^ swz;
        u32 byte1 = (wbase + (u32)((ks+8)*32 + kgrp) * 2u) ^ swz;
        s16x8 b0f = *(const s16x8*)((const char*)Wlds + byte0);
        s16x8 b1f = *(const s16x8*)((const char*)Wlds + byte1);
        na  = __builtin_amdgcn_mfma_f32_16x16x32_bf16(a0, b0f, na,  0, 0, 0);
        nb2 = __builtin_amdgcn_mfma_f32_16x16x32_bf16(a1, b1f, nb2, 0, 0, 0);
      }
      acc_xa_n = na;
      acc_xb_n = nb2;
    }
  }
}

extern "C" void kernel_launch(void* const* d_in, const int* in_sizes, int n_in,
                              void* d_out, int out_size, void* d_ws, size_t ws_size,
                              hipStream_t stream)
{
  const float* xs    = (const float*)d_in[0];
  const float* Wih_f = (const float*)d_in[1];
  const float* Whh_f = (const float*)d_in[2];
  const float* bih_f = (const float*)d_in[3];
  const float* bhh_f = (const float*)d_in[4];
  const float* Wih_b = (const float*)d_in[5];
  const float* Whh_b = (const float*)d_in[6];
  const float* bih_b = (const float*)d_in[7];
  const float* bhh_b = (const float*)d_in[8];
  float* out = (float*)d_out;

  char* ws = (char*)d_ws;
  u32* flags  = (u32*)ws;                        // [8][32] u32 = 1 KB
  u32* roster = (u32*)(ws + 2048);               // [8] u32
  u32* hbuf0  = (u32*)(ws + 4096);               // [2][B][H/2] u32 = 128 KB
  u32* hbuf1  = (u32*)(ws + 4096 + 2*B*(H/2)*4); // 128 KB

  const int init_u32 = (4096 + 2*(2*B*(H/2)*4)) / 4;
  init_ws<<<128, 256, 0, stream>>>((u32*)ws, init_u32);

  lstm_persistent<<<NBLK, 256, 0, stream>>>(
      xs, Wih_f, Whh_f, bih_f, bhh_f,
      Wih_b, Whh_b, bih_b, bhh_b,
      out, flags, roster, hbuf0, hbuf1);
}

// Round 17
// 2585.938 us; speedup vs baseline: 1.0284x; 1.0284x over previous
//
#include <hip/hip_runtime.h>
#include <math.h>

#define B 64
#define T 512
#define II 512
#define H 512
#define NBLK 256
#define POLL_CAP 65536

typedef float f32x4 __attribute__((ext_vector_type(4)));
typedef short s16x8 __attribute__((ext_vector_type(8)));
typedef unsigned u32;
typedef unsigned long long u64;

union pk8 { s16x8 v; u32 u[4]; };

__device__ __forceinline__ unsigned short f2b(float f){
  union { float f; u32 u; } v; v.f = f;
  u32 r = v.u + 0x7fffu + ((v.u >> 16) & 1u);
  return (unsigned short)(r >> 16);
}

__device__ __forceinline__ s16x8 cvt8(float4 lo, float4 hi){
  pk8 r;
  asm("v_cvt_pk_bf16_f32 %0, %1, %2" : "=v"(r.u[0]) : "v"(lo.x), "v"(lo.y));
  asm("v_cvt_pk_bf16_f32 %0, %1, %2" : "=v"(r.u[1]) : "v"(lo.z), "v"(lo.w));
  asm("v_cvt_pk_bf16_f32 %0, %1, %2" : "=v"(r.u[2]) : "v"(hi.x), "v"(hi.y));
  asm("v_cvt_pk_bf16_f32 %0, %1, %2" : "=v"(r.u[3]) : "v"(hi.z), "v"(hi.w));
  return r.v;
}

__device__ __forceinline__ float sigm_(float x){
  return __builtin_amdgcn_rcpf(1.f + __expf(-x));
}
__device__ __forceinline__ float tanh_(float x){
  float t = __expf(-2.f * fabsf(x));
  float r = (1.f - t) * __builtin_amdgcn_rcpf(1.f + t);
  return copysignf(r, x);
}

// ---- XCD-local (L2-scope) ops: sc0 = gfx950 glc (bypass L1, read/write L2) ----
__device__ __forceinline__ u32 ld_sc0_u32(const u32* p){
  u32 v;
  asm volatile("global_load_dword %0, %1, off sc0\n\ts_waitcnt vmcnt(0)"
               : "=v"(v) : "v"(p) : "memory");
  return v;
}
__device__ __forceinline__ void st_sc0_u32(u32* p, u32 v){
  asm volatile("global_store_dword %0, %1, off sc0" : : "v"(p), "v"(v) : "memory");
}
__device__ __forceinline__ void ld4_sc0_issue(const void* p0, const void* p1,
                                              const void* p2, const void* p3,
                                              uint4& a, uint4& b, uint4& c, uint4& d){
  asm volatile(
    "global_load_dwordx4 %0, %4, off sc0\n\t"
    "global_load_dwordx4 %1, %5, off sc0\n\t"
    "global_load_dwordx4 %2, %6, off sc0\n\t"
    "global_load_dwordx4 %3, %7, off sc0"
    : "=&v"(a), "=&v"(b), "=&v"(c), "=&v"(d)
    : "v"(p0), "v"(p1), "v"(p2), "v"(p3)
    : "memory");
}

__global__ void init_ws(u32* p, int n){
  int i = blockIdx.x*blockDim.x + threadIdx.x;
  for (; i < n; i += gridDim.x*blockDim.x)
    __hip_atomic_store(p + i, 0u, __ATOMIC_RELAXED, __HIP_MEMORY_SCOPE_AGENT);
}

// Persistent bidirectional LSTM. 256 blocks x 256 threads, 1 block/CU (LDS-forced).
// FINAL (r11 protocol, best passing: 5.06 us/step):
//  - roster role discovery via HW_REG_XCC_ID -> all group traffic XCD-local (L2).
//  - weights (Wih|Whh, bf16, XOR-swizzled) resident in 128 KB LDS for all 512 steps.
//  - c-state in registers; h published as packed 2xbf16 sc0 stores.
//  - per step: wave0 bounded-poll group flag line -> barrier; h sc0-load -> Hlds
//    (swizzled) -> barrier; 16 h-MFMAs seeded with x-half precomputed in the
//    previous step's tail; gates -> LDS -> barrier; elementwise; drain -> barrier
//    -> flag; tail computes next step's x-half (overlaps peers' catch-up).
// Sync floor measured at ~4 us/step across 10 protocol variants (latency-bound,
// not a counter roofline); compute ~1 us/step.
__global__ __launch_bounds__(256, 1) void lstm_persistent(
    const float* __restrict__ xs,
    const float* __restrict__ Wih_f, const float* __restrict__ Whh_f,
    const float* __restrict__ bih_f, const float* __restrict__ bhh_f,
    const float* __restrict__ Wih_b, const float* __restrict__ Whh_b,
    const float* __restrict__ bih_b, const float* __restrict__ bhh_b,
    float* __restrict__ out,
    u32* __restrict__ flags,     // [8 groups][32] u32 = one 128B line per group
    u32* __restrict__ roster,    // [8] claim counters (agent scope, once)
    u32* __restrict__ hbuf0, u32* __restrict__ hbuf1)  // [2][B][H/2] u32 each
{
  __shared__ unsigned short Wlds[4*16*1024];   // 128 KB bf16, swizzled
  __shared__ unsigned short Hlds[16*512];      // 16 KB bf16, swizzled
  __shared__ float g_lds[4][16][16];
  __shared__ float bias_s[64];
  __shared__ u32 role_s;

  const int tid = threadIdx.x;

  // ---- role discovery: physical XCD id + roster slot (one agent RMW, once) ----
  if (tid == 0){
    u32 xcc;
    asm volatile("s_getreg_b32 %0, hwreg(HW_REG_XCC_ID, 0, 32)" : "=s"(xcc));
    xcc &= 7u;
    u32 slot = __hip_atomic_fetch_add(&roster[xcc], 1u,
                                      __ATOMIC_RELAXED, __HIP_MEMORY_SCOPE_AGENT);
    role_s = (xcc << 5) | (slot & 31u);
  }
  __syncthreads();
  const u32 role = role_s;
  const int grp   = role >> 5;        // = physical XCD id
  const int qtile = role & 31;
  const int dir   = grp >> 2;
  const int btile = grp & 3;
  const int q0 = qtile * 16;
  const int b0 = btile * 16;

  const float* __restrict__ Wih = dir ? Wih_b : Wih_f;
  const float* __restrict__ Whh = dir ? Whh_b : Whh_f;
  const float* __restrict__ bih = dir ? bih_b : bih_f;
  const float* __restrict__ bhh = dir ? bhh_b : bhh_f;

  // ---- stage weights into LDS (bf16, XOR-swizzled), once ----
  for (int it = 0; it < 32; ++it){
    int idx = it * 256 + tid;
    int c64 = idx >> 7;
    int k   = (idx & 127) * 8;
    int cg  = (c64 >> 4) * H + q0 + (c64 & 15);
    const float* src = (k < II) ? (Wih + (size_t)cg * II + k)
                                : (Whh + (size_t)cg * H + (k - II));
    float4 lo = *(const float4*)src;
    float4 hi = *(const float4*)(src + 4);
    s16x8 v;
    v[0]=(short)f2b(lo.x); v[1]=(short)f2b(lo.y); v[2]=(short)f2b(lo.z); v[3]=(short)f2b(lo.w);
    v[4]=(short)f2b(hi.x); v[5]=(short)f2b(hi.y); v[6]=(short)f2b(hi.z); v[7]=(short)f2b(hi.w);
    u32 byte = ((u32)c64 * 2048u + (u32)k * 2u) ^ (((u32)(c64 & 7)) << 4);
    *(s16x8*)((char*)Wlds + byte) = v;
  }
  if (tid < 64){
    int g = tid >> 4, jj = tid & 15;
    int cg = g * H + q0 + jj;
    bias_s[tid] = bih[cg] + bhh[cg];
  }
  __syncthreads();

  const int w = tid >> 6;                 // wave = gate type
  const int l = tid & 63;
  const int arow = b0 + (l & 15);
  const int kgrp = (l >> 4) * 8;
  const int c64w = (w << 4) | (l & 15);
  const u32 swz   = ((u32)(c64w & 7)) << 4;
  const u32 wbase = (u32)c64w * 2048u;
  const u32 hrb = (u32)(l & 15) * 1024u;  // Hlds A-frag row base
  const u32 hsz = ((u32)(l & 7)) << 4;

  // Hlds staging: wave w stages rows 4w..4w+3; lane covers 16B of each row
  const int sr = w * 4;
  const int si = l;

  const int eb = tid >> 4;
  const int ej = tid & 15;
  float c_reg = 0.f;

  const size_t hdir = (size_t)dir * (B * (H/2));   // u32 units
  u32* const fl = flags + grp * 32;

  // ---- prologue: x-half for step 0 (seeds step 0's h-MFMA accumulators) ----
  f32x4 acc_xa_n = {0.f,0.f,0.f,0.f}, acc_xb_n = {0.f,0.f,0.f,0.f};
  {
    const int t0 = dir ? (T-1) : 0;
    const float* xrow = xs + ((size_t)arow * T + t0) * II + kgrp;
    #pragma unroll
    for (int ks = 0; ks < 8; ++ks){
      s16x8 a0 = cvt8(*(const float4*)(xrow + ks*32),     *(const float4*)(xrow + ks*32 + 4));
      s16x8 a1 = cvt8(*(const float4*)(xrow + (ks+8)*32), *(const float4*)(xrow + (ks+8)*32 + 4));
      u32 byte0 = (wbase + (u32)(ks*32 + kgrp) * 2u) ^ swz;
      u32 byte1 = (wbase + (u32)((ks+8)*32 + kgrp) * 2u) ^ swz;
      s16x8 b0f = *(const s16x8*)((const char*)Wlds + byte0);
      s16x8 b1f = *(const s16x8*)((const char*)Wlds + byte1);
      acc_xa_n = __builtin_amdgcn_mfma_f32_16x16x32_bf16(a0, b0f, acc_xa_n, 0, 0, 0);
      acc_xb_n = __builtin_amdgcn_mfma_f32_16x16x32_bf16(a1, b1f, acc_xb_n, 0, 0, 0);
    }
  }

  #pragma unroll 1
  for (int s = 0; s < T; ++s){
    const int t = dir ? (T - 1 - s) : s;
    const u32* __restrict__ hin  = (s & 1) ? hbuf1 : hbuf0;
    u32* __restrict__       hout = (s & 1) ? hbuf0 : hbuf1;

    // ---- 1: wave 0 polls group flag line (bounded); barrier releases block ----
    if (s > 0){
      if (w == 0){
        const u32* fp = fl + (l & 31);
        for (int it = 0; it < POLL_CAP; ++it){
          u32 v = ld_sc0_u32(fp);
          if (__all((int)(v >= (u32)s))) break;
          __builtin_amdgcn_s_sleep(2);
        }
      }
      __syncthreads();                   // BARRIER P
    }

    // ---- 2: h loads (4 x dwordx4 sc0, coalesced) -> Hlds (swizzled) ----
    const char* hinb = (const char*)(hin + hdir);
    const char* r0p = hinb + (size_t)(b0 + sr + 0) * 1024 + (size_t)si * 16;
    const char* r1p = r0p + 1024;
    const char* r2p = r0p + 2048;
    const char* r3p = r0p + 3072;
    uint4 hva, hvb, hvc, hvd;
    ld4_sc0_issue(r0p, r1p, r2p, r3p, hva, hvb, hvc, hvd);
    asm volatile("s_waitcnt vmcnt(0)" ::: "memory");
    __builtin_amdgcn_sched_barrier(0);
    {
      u32 byte0 = ((u32)(sr+0) * 1024u + (u32)si * 16u) ^ (((u32)((sr+0) & 7)) << 4);
      u32 byte1 = ((u32)(sr+1) * 1024u + (u32)si * 16u) ^ (((u32)((sr+1) & 7)) << 4);
      u32 byte2 = ((u32)(sr+2) * 1024u + (u32)si * 16u) ^ (((u32)((sr+2) & 7)) << 4);
      u32 byte3 = ((u32)(sr+3) * 1024u + (u32)si * 16u) ^ (((u32)((sr+3) & 7)) << 4);
      *(uint4*)((char*)Hlds + byte0) = hva;
      *(uint4*)((char*)Hlds + byte1) = hvb;
      *(uint4*)((char*)Hlds + byte2) = hvc;
      *(uint4*)((char*)Hlds + byte3) = hvd;
    }
    __syncthreads();                       // BARRIER A

    // ---- 3: h-half MFMAs, accumulators SEEDED with precomputed x-half ----
    f32x4 acc_ha = acc_xa_n, acc_hb = acc_xb_n;
    #pragma unroll
    for (int ks = 0; ks < 8; ++ks){
      u32 hb0 = (hrb + (u32)(ks*64 + (kgrp*2))) ^ hsz;
      u32 hb1 = (hrb + (u32)((ks+8)*64 + (kgrp*2))) ^ hsz;
      s16x8 a0 = *(const s16x8*)((const char*)Hlds + hb0);
      s16x8 a1 = *(const s16x8*)((const char*)Hlds + hb1);
      u32 byte0 = (wbase + (u32)(II + ks*32 + kgrp) * 2u) ^ swz;
      u32 byte1 = (wbase + (u32)(II + (ks+8)*32 + kgrp) * 2u) ^ swz;
      s16x8 b0f = *(const s16x8*)((const char*)Wlds + byte0);
      s16x8 b1f = *(const s16x8*)((const char*)Wlds + byte1);
      acc_ha = __builtin_amdgcn_mfma_f32_16x16x32_bf16(a0, b0f, acc_ha, 0, 0, 0);
      acc_hb = __builtin_amdgcn_mfma_f32_16x16x32_bf16(a1, b1f, acc_hb, 0, 0, 0);
    }

    // ---- 4: gates to LDS ----
    #pragma unroll
    for (int r = 0; r < 4; ++r){
      int bl = (l >> 4) * 4 + r;
      g_lds[w][bl][l & 15] = acc_ha[r] + acc_hb[r];
    }
    __syncthreads();                       // BARRIER B

    // ---- 5: elementwise update; publish packed h (sc0 -> local L2) ----
    float hn;
    {
      float gi = g_lds[0][eb][ej] + bias_s[ej];
      float gf = g_lds[1][eb][ej] + bias_s[16 + ej];
      float gg = g_lds[2][eb][ej] + bias_s[32 + ej];
      float go = g_lds[3][eb][ej] + bias_s[48 + ej];
      float si_ = sigm_(gi);
      float sf  = sigm_(gf);
      float tg  = tanh_(gg);
      float so  = sigm_(go);
      c_reg = sf * c_reg + si_ * tg;
      hn = so * tanh_(c_reg);
      u32 hb = (u32)f2b(hn);
      u32 nb = (u32)__shfl_xor((int)hb, 1, 64);
      if (!(tid & 1)){
        u32* p = hout + hdir + (size_t)(b0 + eb) * (H/2) + (size_t)((q0 + ej) >> 1);
        st_sc0_u32(p, hb | (nb << 16));
      }
    }

    // ---- 6: per-wave store drain, block barrier, then flag (L2-local) ----
    asm volatile("s_waitcnt vmcnt(0)" ::: "memory");
    __syncthreads();                       // BARRIER C
    if (tid == 0 && s + 1 < T)
      st_sc0_u32(&fl[qtile], (u32)(s + 1));

    // ---- 7: tail (overlaps peers' catch-up): out store + NEXT x-half ----
    out[((size_t)(b0+eb) * T + t) * (2*H) + (size_t)dir * H + (q0 + ej)] = hn;
    if (s + 1 < T){
      const int tn = dir ? (T - 2 - s) : (s + 1);
      const float* xrow = xs + ((size_t)arow * T + tn) * II + kgrp;
      f32x4 na = {0.f,0.f,0.f,0.f}, nb2 = {0.f,0.f,0.f,0.f};
      #pragma unroll
      for (int ks = 0; ks < 8; ++ks){
        s16x8 a0 = cvt8(*(const float4*)(xrow + ks*32),     *(const float4*)(xrow + ks*32 + 4));
        s16x8 a1 = cvt8(*(const float4*)(xrow + (ks+8)*32), *(const float4*)(xrow + (ks+8)*32 + 4));
        u32 byte0 = (wbase + (u32)(ks*32 + kgrp) * 2u) ^ swz;
        u32 byte1 = (wbase + (u32)((ks+8)*32 + kgrp) * 2u) ^ swz;
        s16x8 b0f = *(const s16x8*)((const char*)Wlds + byte0);
        s16x8 b1f = *(const s16x8*)((const char*)Wlds + byte1);
        na  = __builtin_amdgcn_mfma_f32_16x16x32_bf16(a0, b0f, na,  0, 0, 0);
        nb2 = __builtin_amdgcn_mfma_f32_16x16x32_bf16(a1, b1f, nb2, 0, 0, 0);
      }
      acc_xa_n = na;
      acc_xb_n = nb2;
    }
  }
}

extern "C" void kernel_launch(void* const* d_in, const int* in_sizes, int n_in,
                              void* d_out, int out_size, void* d_ws, size_t ws_size,
                              hipStream_t stream)
{
  const float* xs    = (const float*)d_in[0];
  const float* Wih_f = (const float*)d_in[1];
  const float* Whh_f = (const float*)d_in[2];
  const float* bih_f = (const float*)d_in[3];
  const float* bhh_f = (const float*)d_in[4];
  const float* Wih_b = (const float*)d_in[5];
  const float* Whh_b = (const float*)d_in[6];
  const float* bih_b = (const float*)d_in[7];
  const float* bhh_b = (const float*)d_in[8];
  float* out = (float*)d_out;

  char* ws = (char*)d_ws;
  u32* flags  = (u32*)ws;                        // [8][32] u32 = 1 KB
  u32* roster = (u32*)(ws + 2048);               // [8] u32
  u32* hbuf0  = (u32*)(ws + 4096);               // [2][B][H/2] u32 = 128 KB
  u32* hbuf1  = (u32*)(ws + 4096 + 2*B*(H/2)*4); // 128 KB

  const int init_u32 = (4096 + 2*(2*B*(H/2)*4)) / 4;
  init_ws<<<128, 256, 0, stream>>>((u32*)ws, init_u32);

  lstm_persistent<<<NBLK, 256, 0, stream>>>(
      xs, Wih_f, Whh_f, bih_f, bhh_f,
      Wih_b, Whh_b, bih_b, bhh_b,
      out, flags, roster, hbuf0, hbuf1);
}